// Round 1
// baseline (428.143 us; speedup 1.0000x reference)
//
#include <hip/hip_runtime.h>
#include <hip/hip_bf16.h>

#define B_    16
#define L_    2048
#define BL    (B_ * L_)
#define DM    64
#define DS    16
#define HD    16
#define DI    128
#define NH    8
#define INW   296
#define XBC_  160
#define CONVK 4
#define NAGG  10
#define NACT  6
#define CS    128   // chunk size for scan
#define NC    (L_ / CS)

// ---------------------------------------------------------------------------
// Kernel A: embedding gather + proj_in (80 x 64) + bias -> x (BL, 64)
// ---------------------------------------------------------------------------
__global__ __launch_bounds__(256) void k_embed(
    const int* __restrict__ aggs, const float* __restrict__ pegE,
    const float* __restrict__ countE, const float* __restrict__ topE,
    const float* __restrict__ W, const float* __restrict__ bias,
    float* __restrict__ x) {
  __shared__ float e[16][80];
  const int row0 = blockIdx.x * 16;
  const int t = threadIdx.x;
  if (t < 160) {
    int r = t / 10, i = t % 10;
    const float* tab = (i == 0 || i == 1 || i == 9) ? pegE
                       : (i >= 5 && i <= 7)         ? topE
                                                    : countE;
    int idx = aggs[(row0 + r) * NAGG + i];
    const float* src = tab + idx * 8;
#pragma unroll
    for (int j = 0; j < 8; ++j) e[r][i * 8 + j] = src[j];
  }
  __syncthreads();
  const int c = t & 63, rg = t >> 6;
  float acc[4] = {0.f, 0.f, 0.f, 0.f};
  for (int k = 0; k < 80; ++k) {
    float wk = W[k * 64 + c];
#pragma unroll
    for (int j = 0; j < 4; ++j) acc[j] += e[rg + j * 4][k] * wk;
  }
  float bc = bias[c];
#pragma unroll
  for (int j = 0; j < 4; ++j) x[(row0 + rg + j * 4) * 64 + c] = acc[j] + bc;
}

// ---------------------------------------------------------------------------
// Kernel B: RMSNorm + in_proj (64 x 296) -> zxbcdt (BL, 296)
// ---------------------------------------------------------------------------
__global__ __launch_bounds__(256) void k_inproj(
    const float* __restrict__ x, const float* __restrict__ rms_w,
    const float* __restrict__ W, float* __restrict__ out) {
  __shared__ float xn[16][64];
  const int row0 = blockIdx.x * 16;
  const int t = threadIdx.x;
  const int r = t >> 4, l = t & 15;  // 16 threads per row
  float v[4];
  float ss = 0.f;
#pragma unroll
  for (int j = 0; j < 4; ++j) {
    v[j] = x[(row0 + r) * 64 + l * 4 + j];
    ss += v[j] * v[j];
  }
#pragma unroll
  for (int o = 1; o < 16; o <<= 1) ss += __shfl_xor(ss, o, 64);
  float inv = rsqrtf(ss * (1.0f / 64.0f) + 1e-6f);
#pragma unroll
  for (int j = 0; j < 4; ++j) xn[r][l * 4 + j] = v[j] * inv * rms_w[l * 4 + j];
  __syncthreads();
  for (int c = t; c < INW; c += 256) {
    float acc[16];
#pragma unroll
    for (int r2 = 0; r2 < 16; ++r2) acc[r2] = 0.f;
    for (int k = 0; k < 64; ++k) {
      float wk = W[k * INW + c];
#pragma unroll
      for (int r2 = 0; r2 < 16; ++r2) acc[r2] += xn[r2][k] * wk;
    }
#pragma unroll
    for (int r2 = 0; r2 < 16; ++r2) out[(row0 + r2) * INW + c] = acc[r2];
  }
}

// ---------------------------------------------------------------------------
// Kernel C: causal depthwise conv(K=4) + bias + silu; RoPE on B/C; dt,a
// ---------------------------------------------------------------------------
__global__ __launch_bounds__(256) void k_conv(
    const float* __restrict__ zx, const float* __restrict__ conv_w,
    const float* __restrict__ conv_b, const float* __restrict__ dt_bias,
    const float* __restrict__ A_log, float* __restrict__ xs,
    float* __restrict__ Bmr, float* __restrict__ Cmr,
    float* __restrict__ a_arr, float* __restrict__ hd_arr) {
  __shared__ float bc[16][32];
  const int row0 = blockIdx.x * 16;
  const int t = threadIdx.x;
  for (int idx = t; idx < 16 * XBC_; idx += 256) {
    int c = idx % XBC_;
    int rr = idx / XBC_;
    int row = row0 + rr;
    int tpos = row & (L_ - 1);
    float acc = conv_b[c];
#pragma unroll
    for (int k = 0; k < CONVK; ++k) {
      int tt = tpos - 3 + k;
      if (tt >= 0) acc += zx[(row - 3 + k) * INW + 128 + c] * conv_w[c * 4 + k];
    }
    float s = acc / (1.0f + __expf(-acc));  // silu
    if (c < 128)
      xs[row * 128 + c] = s;
    else
      bc[rr][c - 128] = s;
  }
  __syncthreads();
  // RoPE: 16 rows x 16 tasks
  {
    int rr = t >> 4, j = t & 15;
    int row = row0 + rr;
    int tpos = row & (L_ - 1);
    int i = j & 7;
    float invf = powf(10000.0f, -(float)i * 0.125f);
    float ang = (float)tpos * invf;
    float sn = sinf(ang), cs = cosf(ang);
    if (j < 8) {
      float b1 = bc[rr][i], b2 = bc[rr][i + 8];
      Bmr[row * 16 + i] = b1 * cs - b2 * sn;
      Bmr[row * 16 + i + 8] = b1 * sn + b2 * cs;
    } else {
      float c1 = bc[rr][16 + i], c2 = bc[rr][24 + i];
      Cmr[row * 16 + i] = c1 * cs - c2 * sn;
      Cmr[row * 16 + i + 8] = c1 * sn + c2 * cs;
    }
  }
  // dt / a: 16 rows x 8 heads = 128 tasks
  if (t < 128) {
    int rr = t >> 3, h = t & 7;
    int row = row0 + rr;
    float dtr = zx[row * INW + 288 + h] + dt_bias[h];
    float dt = log1pf(expf(dtr));  // softplus
    float a = expf(-expf(A_log[h]) * dt);
    a_arr[row * 8 + h] = a;
    hd_arr[row * 8 + h] = 0.5f * dt;
  }
}

// ---------------------------------------------------------------------------
// Kernel D: scan phase 1 — per-chunk local scan. One wave per (b,h,chunk).
// lane = p*4 + ng; each lane owns state n = ng*4 .. ng*4+3
// ---------------------------------------------------------------------------
__global__ __launch_bounds__(64) void k_scan1(
    const float* __restrict__ xs, const float* __restrict__ Bmr,
    const float* __restrict__ Cmr, const float* __restrict__ a_arr,
    const float* __restrict__ hd_arr, float* __restrict__ yloc,
    float* __restrict__ cum_arr, float* __restrict__ hend,
    float* __restrict__ aprod) {
  const int bid = blockIdx.x;
  const int ck = bid % NC, bh = bid / NC;
  const int h = bh % NH, b = bh / NH;
  const int lane = threadIdx.x;
  const int p = lane >> 2, ng = lane & 3;
  const int rowbase = b * L_;
  const int t0 = ck * CS;

  float hst[4] = {0.f, 0.f, 0.f, 0.f};
  float bxp[4] = {0.f, 0.f, 0.f, 0.f};
  if (t0 > 0) {
    int rp = rowbase + t0 - 1;
    float xp = xs[rp * 128 + h * 16 + p];
    float4 Bp = *(const float4*)(Bmr + rp * 16 + ng * 4);
    bxp[0] = xp * Bp.x;
    bxp[1] = xp * Bp.y;
    bxp[2] = xp * Bp.z;
    bxp[3] = xp * Bp.w;
  }
  float cum = 1.0f;
  for (int i = 0; i < CS; ++i) {
    const int row = rowbase + t0 + i;
    float xv = xs[row * 128 + h * 16 + p];
    float4 Bv = *(const float4*)(Bmr + row * 16 + ng * 4);
    float4 Cv = *(const float4*)(Cmr + row * 16 + ng * 4);
    float av = a_arr[row * 8 + h];
    float hd = hd_arr[row * 8 + h];
    float bx[4] = {xv * Bv.x, xv * Bv.y, xv * Bv.z, xv * Bv.w};
    float y = 0.f;
    float C[4] = {Cv.x, Cv.y, Cv.z, Cv.w};
#pragma unroll
    for (int j = 0; j < 4; ++j) {
      hst[j] = av * hst[j] + hd * (bx[j] + av * bxp[j]);
      y += hst[j] * C[j];
      bxp[j] = bx[j];
    }
    cum *= av;
    y += __shfl_xor(y, 1, 64);
    y += __shfl_xor(y, 2, 64);
    if (ng == 0) yloc[row * 128 + h * 16 + p] = y;
    if (lane == 0) cum_arr[row * 8 + h] = cum;
  }
  const int cbase = (bh * NC + ck) * 256;
#pragma unroll
  for (int j = 0; j < 4; ++j) hend[cbase + p * 16 + ng * 4 + j] = hst[j];
  if (lane == 0) aprod[bh * NC + ck] = cum;
}

// ---------------------------------------------------------------------------
// Kernel E: scan phase 2 — sequential chunk combine per (b,h)
// ---------------------------------------------------------------------------
__global__ __launch_bounds__(256) void k_scan2(const float* __restrict__ hend,
                                               const float* __restrict__ aprod,
                                               float* __restrict__ hstart) {
  const int bh = blockIdx.x;
  const int t = threadIdx.x;
  float hs = 0.f;
  for (int c = 0; c < NC; ++c) {
    hstart[(bh * NC + c) * 256 + t] = hs;
    hs = aprod[bh * NC + c] * hs + hend[(bh * NC + c) * 256 + t];
  }
}

// ---------------------------------------------------------------------------
// Kernel F: y correction + gate (silu(z)) + out_proj (128x64) + residual
// ---------------------------------------------------------------------------
__global__ __launch_bounds__(256) void k_out(
    const float* __restrict__ yloc, const float* __restrict__ cum_arr,
    const float* __restrict__ hstart, const float* __restrict__ Cmr,
    const float* __restrict__ xs, const float* __restrict__ zx,
    const float* __restrict__ Dp, const float* __restrict__ W,
    float* __restrict__ x) {
  __shared__ float g[16][128];
  const int row0 = blockIdx.x * 16;
  const int t = threadIdx.x;
  const int b = row0 / L_;
  const int ck = (row0 & (L_ - 1)) / CS;
  for (int idx = t; idx < 16 * 128; idx += 256) {
    int hp = idx & 127, rr = idx >> 7;
    int row = row0 + rr;
    int hh = hp >> 4, p = hp & 15;
    const float* hs = hstart + ((b * NH + hh) * NC + ck) * 256 + p * 16;
    const float* C = Cmr + row * 16;
    float dot = 0.f;
#pragma unroll
    for (int n = 0; n < 16; ++n) dot += hs[n] * C[n];
    float y = yloc[row * 128 + hp] + cum_arr[row * 8 + hh] * dot +
              Dp[hh] * xs[row * 128 + hp];
    float zv = zx[row * INW + hp];
    g[rr][hp] = y * (zv / (1.0f + __expf(-zv)));
  }
  __syncthreads();
  const int c = t & 63, rg = t >> 6;
  float acc[4] = {0.f, 0.f, 0.f, 0.f};
  for (int k = 0; k < 128; ++k) {
    float wk = W[k * 64 + c];
#pragma unroll
    for (int j = 0; j < 4; ++j) acc[j] += g[rg + j * 4][k] * wk;
  }
#pragma unroll
  for (int j = 0; j < 4; ++j) {
    int row = row0 + rg + j * 4;
    x[row * 64 + c] += acc[j];
  }
}

// ---------------------------------------------------------------------------
// Kernel G: final LayerNorm + head (64 x 6) + bias -> out (BL, 6)
// ---------------------------------------------------------------------------
__global__ __launch_bounds__(256) void k_head(
    const float* __restrict__ x, const float* __restrict__ ln_g,
    const float* __restrict__ ln_b, const float* __restrict__ W,
    const float* __restrict__ bias, float* __restrict__ out) {
  __shared__ float xn[4][64];
  const int t = threadIdx.x;
  const int r = t >> 6, k = t & 63;
  const int row = blockIdx.x * 4 + r;
  float v = x[row * 64 + k];
  float mu = v;
#pragma unroll
  for (int o = 1; o < 64; o <<= 1) mu += __shfl_xor(mu, o, 64);
  mu *= (1.0f / 64.0f);
  float d = v - mu;
  float var = d * d;
#pragma unroll
  for (int o = 1; o < 64; o <<= 1) var += __shfl_xor(var, o, 64);
  var *= (1.0f / 64.0f);
  xn[r][k] = d * rsqrtf(var + 1e-5f) * ln_g[k] + ln_b[k];
  __syncthreads();
  if (k < NACT) {
    float acc = bias[k];
    for (int kk = 0; kk < 64; ++kk) acc += xn[r][kk] * W[kk * NACT + k];
    out[row * NACT + k] = acc;
  }
}

// ---------------------------------------------------------------------------
extern "C" void kernel_launch(void* const* d_in, const int* in_sizes, int n_in,
                              void* d_out, int out_size, void* d_ws,
                              size_t ws_size, hipStream_t stream) {
  const int* aggs = (const int*)d_in[0];
  const float* pegE = (const float*)d_in[1];
  const float* countE = (const float*)d_in[2];
  const float* topE = (const float*)d_in[3];
  const float* proj_in_w = (const float*)d_in[4];
  const float* proj_in_b = (const float*)d_in[5];
  const float* rms_w = (const float*)d_in[6];
  const float* in_w = (const float*)d_in[7];
  const float* conv_w = (const float*)d_in[8];
  const float* conv_b = (const float*)d_in[9];
  const float* dt_bias = (const float*)d_in[10];
  const float* A_log = (const float*)d_in[11];
  const float* Dp = (const float*)d_in[12];
  const float* outp_w = (const float*)d_in[13];
  const float* ln_g = (const float*)d_in[14];
  const float* ln_b = (const float*)d_in[15];
  const float* out_w = (const float*)d_in[16];
  const float* out_b = (const float*)d_in[17];
  float* out = (float*)d_out;

  float* ws = (float*)d_ws;
  size_t off = 0;
  float* x = ws + off;       off += (size_t)BL * 64;
  float* zx = ws + off;      off += (size_t)BL * INW;
  float* xs = ws + off;      off += (size_t)BL * 128;
  float* Bmr = ws + off;     off += (size_t)BL * 16;
  float* Cmr = ws + off;     off += (size_t)BL * 16;
  float* a_arr = ws + off;   off += (size_t)BL * 8;
  float* hd_arr = ws + off;  off += (size_t)BL * 8;
  float* yloc = ws + off;    off += (size_t)BL * 128;
  float* cum_arr = ws + off; off += (size_t)BL * 8;
  float* hend = ws + off;    off += (size_t)B_ * NH * NC * 256;
  float* aprod = ws + off;   off += (size_t)B_ * NH * NC;
  float* hstart = ws + off;  off += (size_t)B_ * NH * NC * 256;

  k_embed<<<BL / 16, 256, 0, stream>>>(aggs, pegE, countE, topE, proj_in_w,
                                       proj_in_b, x);
  for (int l = 0; l < 2; ++l) {
    k_inproj<<<BL / 16, 256, 0, stream>>>(x, rms_w + l * 64,
                                          in_w + (size_t)l * 64 * INW, zx);
    k_conv<<<BL / 16, 256, 0, stream>>>(zx, conv_w + l * XBC_ * 4,
                                        conv_b + l * XBC_, dt_bias + l * 8,
                                        A_log + l * 8, xs, Bmr, Cmr, a_arr,
                                        hd_arr);
    k_scan1<<<B_ * NH * NC, 64, 0, stream>>>(xs, Bmr, Cmr, a_arr, hd_arr, yloc,
                                             cum_arr, hend, aprod);
    k_scan2<<<B_ * NH, 256, 0, stream>>>(hend, aprod, hstart);
    k_out<<<BL / 16, 256, 0, stream>>>(yloc, cum_arr, hstart, Cmr, xs, zx,
                                       Dp + l * 8, outp_w + (size_t)l * 128 * 64,
                                       x);
  }
  k_head<<<BL / 4, 256, 0, stream>>>(x, ln_g, ln_b, out_w, out_b, out);
}

// Round 5
// 371.059 us; speedup vs baseline: 1.1538x; 1.1538x over previous
//
#include <hip/hip_runtime.h>
#include <hip/hip_bf16.h>

#define B_    16
#define L_    2048
#define BL    (B_ * L_)
#define DM    64
#define DS    16
#define HD    16
#define DI    128
#define NH    8
#define INW   296
#define XBC_  160
#define CONVK 4
#define NAGG  10
#define NACT  6
#define CS    64    // chunk size for scan
#define NC    (L_ / CS)   // 32

// ---------------------------------------------------------------------------
// Kernel A: embedding gather + proj_in (80 x 64) + bias -> x (BL, 64)
// ---------------------------------------------------------------------------
__global__ __launch_bounds__(256) void k_embed(
    const int* __restrict__ aggs, const float* __restrict__ pegE,
    const float* __restrict__ countE, const float* __restrict__ topE,
    const float* __restrict__ W, const float* __restrict__ bias,
    float* __restrict__ x) {
  __shared__ float e[16][80];
  const int row0 = blockIdx.x * 16;
  const int t = threadIdx.x;
  if (t < 160) {
    int r = t / 10, i = t % 10;
    const float* tab = (i == 0 || i == 1 || i == 9) ? pegE
                       : (i >= 5 && i <= 7)         ? topE
                                                    : countE;
    int idx = aggs[(row0 + r) * NAGG + i];
    const float* src = tab + idx * 8;
#pragma unroll
    for (int j = 0; j < 8; ++j) e[r][i * 8 + j] = src[j];
  }
  __syncthreads();
  const int c = t & 63, rg = t >> 6;
  float acc[4] = {0.f, 0.f, 0.f, 0.f};
  const float* Wc = W + c;
  for (int k = 0; k < 80; k += 4) {
    float w0 = Wc[k * 64], w1 = Wc[(k + 1) * 64], w2 = Wc[(k + 2) * 64],
          w3 = Wc[(k + 3) * 64];
#pragma unroll
    for (int j = 0; j < 4; ++j) {
      float4 ev = *(const float4*)&e[rg + j * 4][k];
      acc[j] = fmaf(ev.x, w0, acc[j]);
      acc[j] = fmaf(ev.y, w1, acc[j]);
      acc[j] = fmaf(ev.z, w2, acc[j]);
      acc[j] = fmaf(ev.w, w3, acc[j]);
    }
  }
  float bc = bias[c];
#pragma unroll
  for (int j = 0; j < 4; ++j) x[(size_t)(row0 + rg + j * 4) * 64 + c] = acc[j] + bc;
}

// ---------------------------------------------------------------------------
// Kernel B: RMSNorm + in_proj (64 x 296) -> zxbcdt (BL, 296)
// ---------------------------------------------------------------------------
__global__ __launch_bounds__(256) void k_inproj(
    const float* __restrict__ x, const float* __restrict__ rms_w,
    const float* __restrict__ W, float* __restrict__ out) {
  __shared__ float xn[16][64];
  const int row0 = blockIdx.x * 16;
  const int t = threadIdx.x;
  const int r = t >> 4, l = t & 15;  // 16 threads per row
  float4 v = *(const float4*)&x[(size_t)(row0 + r) * 64 + l * 4];
  float ss = v.x * v.x + v.y * v.y + v.z * v.z + v.w * v.w;
#pragma unroll
  for (int o = 1; o < 16; o <<= 1) ss += __shfl_xor(ss, o, 64);
  float inv = rsqrtf(ss * (1.0f / 64.0f) + 1e-6f);
  xn[r][l * 4 + 0] = v.x * inv * rms_w[l * 4 + 0];
  xn[r][l * 4 + 1] = v.y * inv * rms_w[l * 4 + 1];
  xn[r][l * 4 + 2] = v.z * inv * rms_w[l * 4 + 2];
  xn[r][l * 4 + 3] = v.w * inv * rms_w[l * 4 + 3];
  __syncthreads();
  for (int c = t; c < INW; c += 256) {
    float acc[16];
#pragma unroll
    for (int r2 = 0; r2 < 16; ++r2) acc[r2] = 0.f;
    const float* Wc = W + c;
    for (int k = 0; k < 64; k += 4) {
      float w0 = Wc[k * INW], w1 = Wc[(k + 1) * INW], w2 = Wc[(k + 2) * INW],
            w3 = Wc[(k + 3) * INW];
#pragma unroll
      for (int r2 = 0; r2 < 16; ++r2) {
        float4 xv = *(const float4*)&xn[r2][k];
        acc[r2] = fmaf(xv.x, w0, acc[r2]);
        acc[r2] = fmaf(xv.y, w1, acc[r2]);
        acc[r2] = fmaf(xv.z, w2, acc[r2]);
        acc[r2] = fmaf(xv.w, w3, acc[r2]);
      }
    }
#pragma unroll
    for (int r2 = 0; r2 < 16; ++r2) out[(size_t)(row0 + r2) * INW + c] = acc[r2];
  }
}

// ---------------------------------------------------------------------------
// Kernel C: causal depthwise conv(K=4) + bias + silu; RoPE on B/C; dt,a
// ---------------------------------------------------------------------------
__global__ __launch_bounds__(256) void k_conv(
    const float* __restrict__ zx, const float* __restrict__ conv_w,
    const float* __restrict__ conv_b, const float* __restrict__ dt_bias,
    const float* __restrict__ A_log, float* __restrict__ xs,
    float* __restrict__ Bmr, float* __restrict__ Cmr,
    float2* __restrict__ ahd) {
  __shared__ float s_zx[19][160];
  __shared__ float s_cw[640];
  __shared__ float s_cb[160];
  __shared__ float bc[16][32];
  const int row0 = blockIdx.x * 16;
  const int t = threadIdx.x;
  for (int idx = t; idx < 19 * 160; idx += 256) {
    int rr = idx / 160, c = idx - rr * 160;
    int row = row0 - 3 + rr;
    s_zx[rr][c] = (row >= 0) ? zx[(size_t)row * INW + 128 + c] : 0.f;
  }
  for (int idx = t; idx < 640; idx += 256) s_cw[idx] = conv_w[idx];
  if (t < 160) s_cb[t] = conv_b[t];
  __syncthreads();
  for (int idx = t; idx < 16 * XBC_; idx += 256) {
    int rr = idx / 160, c = idx - rr * 160;
    int row = row0 + rr;
    int tpos = row & (L_ - 1);
    float acc = s_cb[c];
#pragma unroll
    for (int k = 0; k < CONVK; ++k) {
      if (tpos - 3 + k >= 0) acc = fmaf(s_zx[rr + k][c], s_cw[c * 4 + k], acc);
    }
    float s = acc / (1.0f + __expf(-acc));  // silu
    if (c < 128)
      xs[(size_t)row * 128 + c] = s;
    else
      bc[rr][c - 128] = s;
  }
  __syncthreads();
  // RoPE: 16 rows x 16 tasks
  {
    int rr = t >> 4, j = t & 15;
    int row = row0 + rr;
    int tpos = row & (L_ - 1);
    int i = j & 7;
    float invf = exp2f(-(float)i * 1.66096404744368f);  // 10000^(-i/8)
    float ang = (float)tpos * invf;
    float sn = sinf(ang), cs = cosf(ang);
    if (j < 8) {
      float b1 = bc[rr][i], b2 = bc[rr][i + 8];
      Bmr[(size_t)row * 16 + i] = b1 * cs - b2 * sn;
      Bmr[(size_t)row * 16 + i + 8] = b1 * sn + b2 * cs;
    } else {
      float c1 = bc[rr][16 + i], c2 = bc[rr][24 + i];
      Cmr[(size_t)row * 16 + i] = c1 * cs - c2 * sn;
      Cmr[(size_t)row * 16 + i + 8] = c1 * sn + c2 * cs;
    }
  }
  // dt / a: 16 rows x 8 heads = 128 tasks
  if (t < 128) {
    int rr = t >> 3, h = t & 7;
    int row = row0 + rr;
    float dtr = zx[(size_t)row * INW + 288 + h] + dt_bias[h];
    float dt = (dtr > 20.f) ? dtr : log1pf(__expf(dtr));  // softplus
    float a = __expf(-__expf(A_log[h]) * dt);
    ahd[(size_t)row * 8 + h] = make_float2(a, 0.5f * dt);
  }
}

// ---------------------------------------------------------------------------
// scan step: h = a*h + hd*(bx + a*bx_prev);  y = h . C
// ---------------------------------------------------------------------------
__device__ __forceinline__ void scan_step(float xv, const float Bb[4],
                                          const float Cb[4], float2 ah,
                                          float hst[4], float bxp[4],
                                          float& cum, float& yout) {
  float av = ah.x, hd = ah.y;
  float y = 0.f;
#pragma unroll
  for (int j = 0; j < 4; ++j) {
    float bx = xv * Bb[j];
    float t1 = fmaf(hd, bxp[j], hst[j]);
    hst[j] = fmaf(av, t1, hd * bx);
    y = fmaf(hst[j], Cb[j], y);
    bxp[j] = bx;
  }
  cum *= av;
  yout = y;
}

// ---------------------------------------------------------------------------
// Kernel D: scan phase 1 — per-chunk local scan. One wave per (b,h,chunk),
// 4 waves per block. lane = p*4 + ng; lane owns states n = ng*4 .. ng*4+3
// ---------------------------------------------------------------------------
__global__ __launch_bounds__(256) void k_scan1(
    const float* __restrict__ xs, const float* __restrict__ Bmr,
    const float* __restrict__ Cmr, const float2* __restrict__ ahd,
    float* __restrict__ yloc, float* __restrict__ cum_arr,
    float* __restrict__ hend, float* __restrict__ aprod) {
  const int task = blockIdx.x * 4 + (threadIdx.x >> 6);
  const int ck = task & (NC - 1), bh = task >> 5;  // NC == 32
  const int h = bh & 7, b = bh >> 3;
  const int lane = threadIdx.x & 63;
  const int p = lane >> 2, ng = lane & 3;
  const int t0 = ck * CS;
  const int row0 = b * L_ + t0;

  const float* xp = xs + (size_t)row0 * 128 + h * 16 + p;
  const float* Bp = Bmr + (size_t)row0 * 16 + ng * 4;
  const float* Cp = Cmr + (size_t)row0 * 16 + ng * 4;
  const float2* ap = ahd + (size_t)row0 * 8 + h;
  float* ylp = yloc + (size_t)row0 * 128 + h * 16 + p;
  float* cp = cum_arr + (size_t)row0 * 8 + h;

  float hst[4] = {0.f, 0.f, 0.f, 0.f};
  float bxp[4] = {0.f, 0.f, 0.f, 0.f};
  if (t0 > 0) {
    float xprev = xp[-128];
    float Bprev[4];
    *(float4*)Bprev = *(const float4*)(Bp - 16);
#pragma unroll
    for (int j = 0; j < 4; ++j) bxp[j] = xprev * Bprev[j];
  }
  float cum = 1.0f;
  float xv = xp[0];
  float Bb[4], Cb[4];
  *(float4*)Bb = *(const float4*)Bp;
  *(float4*)Cb = *(const float4*)Cp;
  float2 ah = ap[0];

  for (int i = 0; i < CS - 1; ++i) {
    // prefetch i+1 (independent of the serial chain)
    float xv2 = xp[(size_t)(i + 1) * 128];
    float Bb2[4], Cb2[4];
    *(float4*)Bb2 = *(const float4*)(Bp + (i + 1) * 16);
    *(float4*)Cb2 = *(const float4*)(Cp + (i + 1) * 16);
    float2 ah2 = ap[(size_t)(i + 1) * 8];
    float y;
    scan_step(xv, Bb, Cb, ah, hst, bxp, cum, y);
    y += __shfl_xor(y, 1, 64);
    y += __shfl_xor(y, 2, 64);
    if (ng == 0) ylp[(size_t)i * 128] = y;
    if (lane == 0) cp[(size_t)i * 8] = cum;
    xv = xv2;
    ah = ah2;
#pragma unroll
    for (int j = 0; j < 4; ++j) {
      Bb[j] = Bb2[j];
      Cb[j] = Cb2[j];
    }
  }
  {
    float y;
    scan_step(xv, Bb, Cb, ah, hst, bxp, cum, y);
    y += __shfl_xor(y, 1, 64);
    y += __shfl_xor(y, 2, 64);
    if (ng == 0) ylp[(size_t)(CS - 1) * 128] = y;
    if (lane == 0) cp[(size_t)(CS - 1) * 8] = cum;
  }
  float4 hv = make_float4(hst[0], hst[1], hst[2], hst[3]);
  *(float4*)(hend + (size_t)task * 256 + p * 16 + ng * 4) = hv;
  if (lane == 0) aprod[task] = cum;
}

// ---------------------------------------------------------------------------
// Kernel E: scan phase 2 — sequential chunk combine per (b,h), prefetched
// ---------------------------------------------------------------------------
__global__ __launch_bounds__(256) void k_scan2(const float* __restrict__ hend,
                                               const float* __restrict__ aprod,
                                               float* __restrict__ hstart) {
  const int bh = blockIdx.x;
  const int t = threadIdx.x;
  const float* he = hend + (size_t)bh * NC * 256 + t;
  const float* apr = aprod + bh * NC;
  float* hsp = hstart + (size_t)bh * NC * 256 + t;
  float hs = 0.f;
  float hn = he[0];
  float ap = apr[0];
  for (int c = 0; c < NC; ++c) {
    int c1 = (c + 1 < NC) ? c + 1 : c;
    float hn2 = he[(size_t)c1 * 256];
    float ap2 = apr[c1];
    hsp[(size_t)c * 256] = hs;
    hs = fmaf(ap, hs, hn);
    hn = hn2;
    ap = ap2;
  }
}

// ---------------------------------------------------------------------------
// Kernel F: y correction + gate (silu(z)) + out_proj (128x64) + residual
// ---------------------------------------------------------------------------
__global__ __launch_bounds__(256) void k_out(
    const float* __restrict__ yloc, const float* __restrict__ cum_arr,
    const float* __restrict__ hstart, const float* __restrict__ Cmr,
    const float* __restrict__ xs, const float* __restrict__ zx,
    const float* __restrict__ Dp, const float* __restrict__ W,
    float* __restrict__ x) {
  __shared__ float g[16][128];
  const int row0 = blockIdx.x * 16;
  const int t = threadIdx.x;
  const int b = row0 / L_;
  const int ck = (row0 & (L_ - 1)) / CS;
  for (int idx = t; idx < 16 * 128; idx += 256) {
    int hp = idx & 127, rr = idx >> 7;
    int row = row0 + rr;
    int hh = hp >> 4, p = hp & 15;
    const float4* hs =
        (const float4*)(hstart + ((size_t)(b * NH + hh) * NC + ck) * 256 + p * 16);
    const float4* C4 = (const float4*)(Cmr + (size_t)row * 16);
    float4 h0 = hs[0], h1 = hs[1], h2 = hs[2], h3 = hs[3];
    float4 c0 = C4[0], c1 = C4[1], c2 = C4[2], c3 = C4[3];
    float dot = h0.x * c0.x + h0.y * c0.y + h0.z * c0.z + h0.w * c0.w +
                h1.x * c1.x + h1.y * c1.y + h1.z * c1.z + h1.w * c1.w +
                h2.x * c2.x + h2.y * c2.y + h2.z * c2.z + h2.w * c2.w +
                h3.x * c3.x + h3.y * c3.y + h3.z * c3.z + h3.w * c3.w;
    float y = yloc[(size_t)row * 128 + hp] + cum_arr[(size_t)row * 8 + hh] * dot +
              Dp[hh] * xs[(size_t)row * 128 + hp];
    float zv = zx[(size_t)row * INW + hp];
    g[rr][hp] = y * (zv / (1.0f + __expf(-zv)));
  }
  __syncthreads();
  const int c = t & 63, rg = t >> 6;
  float acc[4] = {0.f, 0.f, 0.f, 0.f};
  const float* Wc = W + c;
  for (int k = 0; k < 128; k += 4) {
    float w0 = Wc[k * 64], w1 = Wc[(k + 1) * 64], w2 = Wc[(k + 2) * 64],
          w3 = Wc[(k + 3) * 64];
#pragma unroll
    for (int j = 0; j < 4; ++j) {
      float4 gv = *(const float4*)&g[rg + j * 4][k];
      acc[j] = fmaf(gv.x, w0, acc[j]);
      acc[j] = fmaf(gv.y, w1, acc[j]);
      acc[j] = fmaf(gv.z, w2, acc[j]);
      acc[j] = fmaf(gv.w, w3, acc[j]);
    }
  }
#pragma unroll
  for (int j = 0; j < 4; ++j) {
    int row = row0 + rg + j * 4;
    x[(size_t)row * 64 + c] += acc[j];
  }
}

// ---------------------------------------------------------------------------
// Kernel G: final LayerNorm + head (64 x 6) + bias -> out (BL, 6)
// ---------------------------------------------------------------------------
__global__ __launch_bounds__(256) void k_head(
    const float* __restrict__ x, const float* __restrict__ ln_g,
    const float* __restrict__ ln_b, const float* __restrict__ W,
    const float* __restrict__ bias, float* __restrict__ out) {
  __shared__ float xn[4][64];
  const int t = threadIdx.x;
  const int r = t >> 6, k = t & 63;
  const int row = blockIdx.x * 4 + r;
  float v = x[(size_t)row * 64 + k];
  float mu = v;
#pragma unroll
  for (int o = 1; o < 64; o <<= 1) mu += __shfl_xor(mu, o, 64);
  mu *= (1.0f / 64.0f);
  float d = v - mu;
  float var = d * d;
#pragma unroll
  for (int o = 1; o < 64; o <<= 1) var += __shfl_xor(var, o, 64);
  var *= (1.0f / 64.0f);
  xn[r][k] = d * rsqrtf(var + 1e-5f) * ln_g[k] + ln_b[k];
  __syncthreads();
  if (k < NACT) {
    float acc = bias[k];
    for (int kk = 0; kk < 64; ++kk) acc = fmaf(xn[r][kk], W[kk * NACT + k], acc);
    out[(size_t)row * NACT + k] = acc;
  }
}

// ---------------------------------------------------------------------------
extern "C" void kernel_launch(void* const* d_in, const int* in_sizes, int n_in,
                              void* d_out, int out_size, void* d_ws,
                              size_t ws_size, hipStream_t stream) {
  const int* aggs = (const int*)d_in[0];
  const float* pegE = (const float*)d_in[1];
  const float* countE = (const float*)d_in[2];
  const float* topE = (const float*)d_in[3];
  const float* proj_in_w = (const float*)d_in[4];
  const float* proj_in_b = (const float*)d_in[5];
  const float* rms_w = (const float*)d_in[6];
  const float* in_w = (const float*)d_in[7];
  const float* conv_w = (const float*)d_in[8];
  const float* conv_b = (const float*)d_in[9];
  const float* dt_bias = (const float*)d_in[10];
  const float* A_log = (const float*)d_in[11];
  const float* Dp = (const float*)d_in[12];
  const float* outp_w = (const float*)d_in[13];
  const float* ln_g = (const float*)d_in[14];
  const float* ln_b = (const float*)d_in[15];
  const float* out_w = (const float*)d_in[16];
  const float* out_b = (const float*)d_in[17];
  float* out = (float*)d_out;

  float* ws = (float*)d_ws;
  size_t off = 0;
  float* x = ws + off;       off += (size_t)BL * 64;
  float* zx = ws + off;      off += (size_t)BL * INW;
  float* xs = ws + off;      off += (size_t)BL * 128;
  float* Bmr = ws + off;     off += (size_t)BL * 16;
  float* Cmr = ws + off;     off += (size_t)BL * 16;
  float2* ahd = (float2*)(ws + off); off += (size_t)BL * 16;  // (a, 0.5*dt)
  float* yloc = ws + off;    off += (size_t)BL * 128;
  float* cum_arr = ws + off; off += (size_t)BL * 8;
  float* hend = ws + off;    off += (size_t)B_ * NH * NC * 256;
  float* aprod = ws + off;   off += (size_t)B_ * NH * NC;
  float* hstart = ws + off;  off += (size_t)B_ * NH * NC * 256;

  k_embed<<<BL / 16, 256, 0, stream>>>(aggs, pegE, countE, topE, proj_in_w,
                                       proj_in_b, x);
  for (int l = 0; l < 2; ++l) {
    k_inproj<<<BL / 16, 256, 0, stream>>>(x, rms_w + l * 64,
                                          in_w + (size_t)l * 64 * INW, zx);
    k_conv<<<BL / 16, 256, 0, stream>>>(zx, conv_w + l * XBC_ * 4,
                                        conv_b + l * XBC_, dt_bias + l * 8,
                                        A_log + l * 8, xs, Bmr, Cmr, ahd);
    k_scan1<<<B_ * NH * NC / 4, 256, 0, stream>>>(xs, Bmr, Cmr, ahd, yloc,
                                                  cum_arr, hend, aprod);
    k_scan2<<<B_ * NH, 256, 0, stream>>>(hend, aprod, hstart);
    k_out<<<BL / 16, 256, 0, stream>>>(yloc, cum_arr, hstart, Cmr, xs, zx,
                                       Dp + l * 8, outp_w + (size_t)l * 128 * 64,
                                       x);
  }
  k_head<<<BL / 4, 256, 0, stream>>>(x, ln_g, ln_b, out_w, out_b, out);
}